// Round 2
// baseline (282.897 us; speedup 1.0000x reference)
//
#include <hip/hip_runtime.h>
#include <math.h>

#define BSZ 4
#define SEQ 4096
#define HID 2048
#define NE 64
#define TOPK 8
#define NTOK (BSZ*SEQ)        // 16384
#define NSPLIT 4
#define KSPL (HID/NSPLIT)     // 512
#define KC 64                 // k-chunk staged in LDS
#define BT 128                // tokens per block

#define XS 66                 // x_lds row stride (floats): 2-way bank alias max, b64-aligned writes
#define WSTR 68               // w_lds row stride (floats): keeps b128 reads 16B-aligned

// ---------------- Kernel 1: gate GEMM, fp64 accumulate, fp32 partials ----------------
__global__ __launch_bounds__(256, 2)
void moe_gate_gemm(const float* __restrict__ x, const float* __restrict__ W,
                   float* __restrict__ part) {
    __shared__ __align__(16) float xlds[BT * XS];
    __shared__ __align__(16) float wlds[KC * WSTR];

    const int tid   = threadIdx.x;
    const int tile  = blockIdx.x;   // 0..127 (token tile)
    const int split = blockIdx.y;   // 0..3   (k split)
    const int T0 = tile * BT;
    const int k0 = split * KSPL;

    const int tx = tid & 15;        // expert group: e0 = tx*4
    const int ty = tid >> 4;        // token group:  t0 = ty*8

    double acc[8][4];
    #pragma unroll
    for (int i = 0; i < 8; i++)
        #pragma unroll
        for (int j = 0; j < 4; j++) acc[i][j] = 0.0;

    for (int c = 0; c < KSPL / KC; c++) {
        const int kc = k0 + c * KC;

        // stage x: 128 tokens x 64 k (row-major, k contiguous)
        {
            const int jt = tid >> 4;   // 0..15
            const int j4 = tid & 15;   // float4 index within 64-k row
            #pragma unroll
            for (int r = 0; r < 8; r++) {
                const int t = jt + r * 16;
                const float4 v = *reinterpret_cast<const float4*>(
                    &x[(size_t)(T0 + t) * HID + kc + j4 * 4]);
                float2* p = reinterpret_cast<float2*>(&xlds[t * XS + j4 * 4]);
                p[0] = make_float2(v.x, v.y);
                p[1] = make_float2(v.z, v.w);
            }
        }
        // stage W transposed: w_lds[k][e]
        {
            const int e = tid >> 2;    // 0..63
            const int q = tid & 3;     // 0..3
            #pragma unroll
            for (int r = 0; r < 4; r++) {
                const int k4 = q + r * 4;   // float4 index 0..15
                const float4 v = *reinterpret_cast<const float4*>(
                    &W[(size_t)e * HID + kc + k4 * 4]);
                wlds[(k4 * 4 + 0) * WSTR + e] = v.x;
                wlds[(k4 * 4 + 1) * WSTR + e] = v.y;
                wlds[(k4 * 4 + 2) * WSTR + e] = v.z;
                wlds[(k4 * 4 + 3) * WSTR + e] = v.w;
            }
        }
        __syncthreads();

        #pragma unroll 4
        for (int k = 0; k < KC; k++) {
            const float4 wv = *reinterpret_cast<const float4*>(&wlds[k * WSTR + tx * 4]);
            float xv[8];
            #pragma unroll
            for (int i = 0; i < 8; i++) xv[i] = xlds[(ty * 8 + i) * XS + k];
            #pragma unroll
            for (int i = 0; i < 8; i++) {
                acc[i][0] += (double)xv[i] * (double)wv.x;
                acc[i][1] += (double)xv[i] * (double)wv.y;
                acc[i][2] += (double)xv[i] * (double)wv.z;
                acc[i][3] += (double)xv[i] * (double)wv.w;
            }
        }
        __syncthreads();
    }

    // write fp32 partials: part[split][token][64]
    #pragma unroll
    for (int i = 0; i < 8; i++) {
        const int tok = T0 + ty * 8 + i;
        const float4 v = make_float4((float)acc[i][0], (float)acc[i][1],
                                     (float)acc[i][2], (float)acc[i][3]);
        *reinterpret_cast<float4*>(
            &part[((size_t)split * NTOK + tok) * NE + tx * 4]) = v;
    }
}

// ---------------- Kernel 2: reduce partials + bias, top-8, masked softmax ----------------
// NOTE: ids are written as FLOAT values — the harness reads the whole d_out
// buffer as float32 (output 0's dtype) before splitting into chunks.
__global__ __launch_bounds__(256)
void moe_topk_softmax(const float* __restrict__ part, const float* __restrict__ b,
                      float* __restrict__ probs, float* __restrict__ ids) {
    const int lane  = threadIdx.x & 63;
    const int w     = threadIdx.x >> 6;
    const int token = blockIdx.x * 4 + w;

    // deterministic fixed-order reduction of the 4 k-split partials
    float g = b[lane];
    #pragma unroll
    for (int s = 0; s < NSPLIT; s++)
        g += part[((size_t)s * NTOK + token) * NE + lane];

    const float gorig = g;
    float cur = g;
    float m = 0.f, denom = 0.f;
    int   myid = 0;
    bool  sel = false;

    #pragma unroll
    for (int it = 0; it < TOPK; it++) {
        // wave argmax with lower-index tie-break (jax.lax.top_k stability)
        float v = cur;
        int idx = lane;
        #pragma unroll
        for (int d = 1; d < 64; d <<= 1) {
            const float ov = __shfl_xor(v, d, 64);
            const int   oi = __shfl_xor(idx, d, 64);
            if (ov > v || (ov == v && oi < idx)) { v = ov; idx = oi; }
        }
        if (it == 0) m = v;
        denom += expf(v - m);
        if (lane == idx) { sel = true; cur = -INFINITY; }
        if (lane == it)  myid = idx;   // lane `it` holds the it-th id (descending order)
    }

    probs[(size_t)token * NE + lane] = sel ? expf(gorig - m) / denom : 0.f;
    if (lane < TOPK) ids[(size_t)token * TOPK + lane] = (float)myid;
}

// ---------------- launch ----------------
extern "C" void kernel_launch(void* const* d_in, const int* in_sizes, int n_in,
                              void* d_out, int out_size, void* d_ws, size_t ws_size,
                              hipStream_t stream) {
    const float* x = (const float*)d_in[0];
    const float* W = (const float*)d_in[1];
    const float* b = (const float*)d_in[2];

    float* probs = (float*)d_out;                         // NTOK*NE floats
    float* ids   = (float*)d_out + (size_t)NTOK * NE;     // NTOK*TOPK, written as float
    float* part  = (float*)d_ws;                          // NSPLIT*NTOK*NE floats = 16 MiB

    dim3 g1(NTOK / BT, NSPLIT);
    moe_gate_gemm<<<g1, 256, 0, stream>>>(x, W, part);
    moe_topk_softmax<<<NTOK / 4, 256, 0, stream>>>(part, b, probs, ids);
}

// Round 3
// 280.075 us; speedup vs baseline: 1.0101x; 1.0101x over previous
//
#include <hip/hip_runtime.h>
#include <math.h>

#define BSZ 4
#define SEQ 4096
#define HID 2048
#define NE 64
#define TOPK 8
#define NTOK (BSZ*SEQ)        // 16384
#define NSPLIT 4
#define KSPL (HID/NSPLIT)     // 512
#define KC 64                 // k-chunk staged in LDS
#define BT 64                 // tokens per block

#define XS 68                 // xlds row stride [k][t] (floats) — keeps b128 reads 16B-aligned
#define WSS 68                // wlds row stride [k][e]

// ---------------- Kernel 1: gate GEMM, both operands k-major in LDS ----------------
// Per k: 2x ds_read_b128 + 16 fp64 FMA per thread. 4 blocks/CU.
__global__ __launch_bounds__(256, 4)
void moe_gate_gemm(const float* __restrict__ x, const float* __restrict__ W,
                   float* __restrict__ part) {
    __shared__ __align__(16) float xlds[KC * XS];
    __shared__ __align__(16) float wlds[KC * WSS];

    const int tid   = threadIdx.x;
    const int tile  = blockIdx.x;   // 0..255 (token tile)
    const int split = blockIdx.y;   // 0..3   (k split)
    const int T0 = tile * BT;
    const int k0 = split * KSPL;

    const int tx = tid & 15;        // expert group: e0 = tx*4
    const int ty = tid >> 4;        // token group:  t0 = ty*4

    const int row = tid & 63;       // staging: token row (x) / expert row (W)
    const int q   = tid >> 6;       // wave id 0..3

    double acc[4][4];
    #pragma unroll
    for (int i = 0; i < 4; i++)
        #pragma unroll
        for (int j = 0; j < 4; j++) acc[i][j] = 0.0;

    for (int c = 0; c < KSPL / KC; c++) {
        const int kc = k0 + c * KC;

        // stage x^T and W^T: [k][row] layouts, lane-consecutive writes (conflict-free)
        #pragma unroll
        for (int r = 0; r < 4; r++) {
            const int k4 = r * 4 + q;   // 0..15; block's 4 waves cover one 64B line/pass
            const float4 xv = *reinterpret_cast<const float4*>(
                &x[(size_t)(T0 + row) * HID + kc + k4 * 4]);
            xlds[(k4 * 4 + 0) * XS + row] = xv.x;
            xlds[(k4 * 4 + 1) * XS + row] = xv.y;
            xlds[(k4 * 4 + 2) * XS + row] = xv.z;
            xlds[(k4 * 4 + 3) * XS + row] = xv.w;
            const float4 wv = *reinterpret_cast<const float4*>(
                &W[(size_t)row * HID + kc + k4 * 4]);
            wlds[(k4 * 4 + 0) * WSS + row] = wv.x;
            wlds[(k4 * 4 + 1) * WSS + row] = wv.y;
            wlds[(k4 * 4 + 2) * WSS + row] = wv.z;
            wlds[(k4 * 4 + 3) * WSS + row] = wv.w;
        }
        __syncthreads();

        #pragma unroll 4
        for (int k = 0; k < KC; k++) {
            const float4 xv = *reinterpret_cast<const float4*>(&xlds[k * XS + ty * 4]);
            const float4 wv = *reinterpret_cast<const float4*>(&wlds[k * WSS + tx * 4]);
            const float xr[4] = {xv.x, xv.y, xv.z, xv.w};
            const float wr[4] = {wv.x, wv.y, wv.z, wv.w};
            #pragma unroll
            for (int i = 0; i < 4; i++)
                #pragma unroll
                for (int j = 0; j < 4; j++)
                    acc[i][j] += (double)xr[i] * (double)wr[j];
        }
        __syncthreads();
    }

    // write fp32 partials: part[split][token][64]
    #pragma unroll
    for (int i = 0; i < 4; i++) {
        const int tok = T0 + ty * 4 + i;
        const float4 v = make_float4((float)acc[i][0], (float)acc[i][1],
                                     (float)acc[i][2], (float)acc[i][3]);
        *reinterpret_cast<float4*>(
            &part[((size_t)split * NTOK + tok) * NE + tx * 4]) = v;
    }
}

// ---------------- Kernel 2: reduce partials + bias, top-8, masked softmax ----------------
// NOTE: ids are written as FLOAT values — the harness reads the whole d_out
// buffer as float32 (output 0's dtype) before splitting into chunks.
__global__ __launch_bounds__(256)
void moe_topk_softmax(const float* __restrict__ part, const float* __restrict__ b,
                      float* __restrict__ probs, float* __restrict__ ids) {
    const int lane  = threadIdx.x & 63;
    const int w     = threadIdx.x >> 6;
    const int token = blockIdx.x * 4 + w;

    // deterministic fixed-order reduction of the 4 k-split partials
    float g = b[lane];
    #pragma unroll
    for (int s = 0; s < NSPLIT; s++)
        g += part[((size_t)s * NTOK + token) * NE + lane];

    const float gorig = g;
    float cur = g;
    float m = 0.f, denom = 0.f;
    int   myid = 0;
    bool  sel = false;

    #pragma unroll
    for (int it = 0; it < TOPK; it++) {
        // wave argmax with lower-index tie-break (jax.lax.top_k stability)
        float v = cur;
        int idx = lane;
        #pragma unroll
        for (int d = 1; d < 64; d <<= 1) {
            const float ov = __shfl_xor(v, d, 64);
            const int   oi = __shfl_xor(idx, d, 64);
            if (ov > v || (ov == v && oi < idx)) { v = ov; idx = oi; }
        }
        if (it == 0) m = v;
        denom += expf(v - m);
        if (lane == idx) { sel = true; cur = -INFINITY; }
        if (lane == it)  myid = idx;   // lane `it` holds the it-th id (descending order)
    }

    probs[(size_t)token * NE + lane] = sel ? expf(gorig - m) / denom : 0.f;
    if (lane < TOPK) ids[(size_t)token * TOPK + lane] = (float)myid;
}

// ---------------- launch ----------------
extern "C" void kernel_launch(void* const* d_in, const int* in_sizes, int n_in,
                              void* d_out, int out_size, void* d_ws, size_t ws_size,
                              hipStream_t stream) {
    const float* x = (const float*)d_in[0];
    const float* W = (const float*)d_in[1];
    const float* b = (const float*)d_in[2];

    float* probs = (float*)d_out;                         // NTOK*NE floats
    float* ids   = (float*)d_out + (size_t)NTOK * NE;     // NTOK*TOPK, written as float
    float* part  = (float*)d_ws;                          // NSPLIT*NTOK*NE floats = 16 MiB

    dim3 g1(NTOK / BT, NSPLIT);
    moe_gate_gemm<<<g1, 256, 0, stream>>>(x, W, part);
    moe_topk_softmax<<<NTOK / 4, 256, 0, stream>>>(part, b, probs, ids);
}

// Round 5
// 249.354 us; speedup vs baseline: 1.1345x; 1.1232x over previous
//
#include <hip/hip_runtime.h>
#include <math.h>

#define BSZ 4
#define SEQ 4096
#define HID 2048
#define NE 64
#define TOPK 8
#define NTOK (BSZ*SEQ)        // 16384
#define NSPLIT 4
#define KSPL (HID/NSPLIT)     // 512
#define KC 64                 // k-chunk staged in LDS
#define BT 64                 // tokens per block

#define XS 72                 // LDS row stride [k][tok]: 72 mod 32 = 8 -> frag reads & staged writes <=2-way (free)
#define WSS 72

typedef double f64x4 __attribute__((ext_vector_type(4)));

// ---------------- Kernel 1: gate GEMM on the fp64 matrix pipe ----------------
// Block: 256 thr (4 waves), 64 tok x 64 exp, k-split 4. Wave w: tokens w*16..w*16+15.
// D-fragment layout is NOT assumed: two probe MFMAs (D[i][j]=i and D[i][j]=j)
// decode each lane's (row, col) per acc register at runtime — robust to any
// bijective fragment mapping (ERRATA #3 class bugs).
__global__ __launch_bounds__(256, 4)
void moe_gate_gemm(const float* __restrict__ x, const float* __restrict__ W,
                   float* __restrict__ part) {
    __shared__ float xlds[KC * XS];   // [k][tok], fp32
    __shared__ float wlds[KC * WSS];  // [k][exp], fp32

    const int tid   = threadIdx.x;
    const int tile  = blockIdx.x;   // 0..255 token tile
    const int split = blockIdx.y;   // 0..3 k split
    const int T0 = tile * BT;
    const int k0 = split * KSPL;

    const int wv   = tid >> 6;      // wave 0..3
    const int lane = tid & 63;
    const int kof  = lane >> 4;     // assumed frag k offset 0..3
    const int col  = lane & 15;     // assumed frag row/col 0..15

    const int srow = tid & 63;      // staging row: token (x) / expert (W)

    // ---- layout calibration: decode D-fragment (row, col) per register ----
    const double a1 = (kof == 0) ? (double)col : 0.0;  // A[i][k] = i at k=0
    const double b1 = (kof == 0) ? 1.0 : 0.0;          // B[k][j] = 1 at k=0
    const double a2 = (kof == 0) ? 1.0 : 0.0;
    const double b2 = (kof == 0) ? (double)col : 0.0;  // B[k][j] = j at k=0
    const f64x4 zero = (f64x4){0.0, 0.0, 0.0, 0.0};
    const f64x4 cal1 = __builtin_amdgcn_mfma_f64_16x16x4f64(a1, b1, zero, 0, 0, 0);
    const f64x4 cal2 = __builtin_amdgcn_mfma_f64_16x16x4f64(a2, b2, zero, 0, 0, 0);
    int drow[4], dcol[4];
    #pragma unroll
    for (int a = 0; a < 4; a++) {
        drow[a] = (int)cal1[a];   // this lane's reg a holds D[drow][dcol]
        dcol[a] = (int)cal2[a];
    }

    f64x4 acc[4];
    #pragma unroll
    for (int nt = 0; nt < 4; nt++) acc[nt] = zero;

    const int base_a = kof * XS  + wv * 16 + col;  // A frag fp32 index (plus kb*4*XS)
    const int base_b = kof * WSS + col;            // B frag base (plus nt*16)

    float4 px[4], pw[4];
    // prologue: load chunk 0
    #pragma unroll
    for (int r = 0; r < 4; r++) {
        const int k4 = wv * 4 + r;
        px[r] = *reinterpret_cast<const float4*>(&x[(size_t)(T0 + srow) * HID + k0 + k4 * 4]);
        pw[r] = *reinterpret_cast<const float4*>(&W[(size_t)srow  * HID + k0 + k4 * 4]);
    }

    for (int c = 0; c < KSPL / KC; c++) {
        __syncthreads();   // previous chunk's compute done; LDS reusable
        #pragma unroll
        for (int r = 0; r < 4; r++) {
            const int k4 = wv * 4 + r;
            xlds[(k4 * 4 + 0) * XS + srow] = px[r].x;
            xlds[(k4 * 4 + 1) * XS + srow] = px[r].y;
            xlds[(k4 * 4 + 2) * XS + srow] = px[r].z;
            xlds[(k4 * 4 + 3) * XS + srow] = px[r].w;
            wlds[(k4 * 4 + 0) * WSS + srow] = pw[r].x;
            wlds[(k4 * 4 + 1) * WSS + srow] = pw[r].y;
            wlds[(k4 * 4 + 2) * WSS + srow] = pw[r].z;
            wlds[(k4 * 4 + 3) * WSS + srow] = pw[r].w;
        }
        // issue next chunk's global loads early (hide HBM latency under MFMA)
        if (c + 1 < KSPL / KC) {
            const int kc = k0 + (c + 1) * KC;
            #pragma unroll
            for (int r = 0; r < 4; r++) {
                const int k4 = wv * 4 + r;
                px[r] = *reinterpret_cast<const float4*>(&x[(size_t)(T0 + srow) * HID + kc + k4 * 4]);
                pw[r] = *reinterpret_cast<const float4*>(&W[(size_t)srow  * HID + kc + k4 * 4]);
            }
        }
        __syncthreads();

        #pragma unroll
        for (int kb = 0; kb < KC / 4; kb++) {
            const double ad = (double)xlds[kb * (4 * XS) + base_a];
            #pragma unroll
            for (int nt = 0; nt < 4; nt++) {
                const double bd = (double)wlds[kb * (4 * WSS) + base_b + nt * 16];
                acc[nt] = __builtin_amdgcn_mfma_f64_16x16x4f64(ad, bd, acc[nt], 0, 0, 0);
            }
        }
    }

    // epilogue: scatter via calibrated (row, col) — layout-proof
    #pragma unroll
    for (int nt = 0; nt < 4; nt++) {
        #pragma unroll
        for (int a = 0; a < 4; a++) {
            const int tok = T0 + wv * 16 + drow[a];
            const int e   = nt * 16 + dcol[a];
            part[((size_t)split * NTOK + tok) * NE + e] = (float)acc[nt][a];
        }
    }
}

// ---------------- Kernel 2: reduce partials + bias, top-8, masked softmax ----------------
// NOTE: ids are written as FLOAT values — the harness reads the whole d_out
// buffer as float32 (output 0's dtype) before splitting into chunks.
__global__ __launch_bounds__(256)
void moe_topk_softmax(const float* __restrict__ part, const float* __restrict__ b,
                      float* __restrict__ probs, float* __restrict__ ids) {
    const int lane  = threadIdx.x & 63;
    const int w     = threadIdx.x >> 6;
    const int token = blockIdx.x * 4 + w;

    // deterministic fixed-order reduction of the 4 k-split partials
    float g = b[lane];
    #pragma unroll
    for (int s = 0; s < NSPLIT; s++)
        g += part[((size_t)s * NTOK + token) * NE + lane];

    const float gorig = g;
    float cur = g;
    float m = 0.f, denom = 0.f;
    int   myid = 0;
    bool  sel = false;

    #pragma unroll
    for (int it = 0; it < TOPK; it++) {
        // wave argmax with lower-index tie-break (jax.lax.top_k stability)
        float v = cur;
        int idx = lane;
        #pragma unroll
        for (int d = 1; d < 64; d <<= 1) {
            const float ov = __shfl_xor(v, d, 64);
            const int   oi = __shfl_xor(idx, d, 64);
            if (ov > v || (ov == v && oi < idx)) { v = ov; idx = oi; }
        }
        if (it == 0) m = v;
        denom += expf(v - m);
        if (lane == idx) { sel = true; cur = -INFINITY; }
        if (lane == it)  myid = idx;   // lane `it` holds the it-th id (descending order)
    }

    probs[(size_t)token * NE + lane] = sel ? expf(gorig - m) / denom : 0.f;
    if (lane < TOPK) ids[(size_t)token * TOPK + lane] = (float)myid;
}

// ---------------- launch ----------------
extern "C" void kernel_launch(void* const* d_in, const int* in_sizes, int n_in,
                              void* d_out, int out_size, void* d_ws, size_t ws_size,
                              hipStream_t stream) {
    const float* x = (const float*)d_in[0];
    const float* W = (const float*)d_in[1];
    const float* b = (const float*)d_in[2];

    float* probs = (float*)d_out;                         // NTOK*NE floats
    float* ids   = (float*)d_out + (size_t)NTOK * NE;     // NTOK*TOPK, written as float
    float* part  = (float*)d_ws;                          // NSPLIT*NTOK*NE floats = 16 MiB

    dim3 g1(NTOK / BT, NSPLIT);
    moe_gate_gemm<<<g1, 256, 0, stream>>>(x, W, part);
    moe_topk_softmax<<<NTOK / 4, 256, 0, stream>>>(part, b, probs, ids);
}

// Round 6
// 248.370 us; speedup vs baseline: 1.1390x; 1.0040x over previous
//
#include <hip/hip_runtime.h>
#include <math.h>

#define BSZ 4
#define SEQ 4096
#define HID 2048
#define NE 64
#define TOPK 8
#define NTOK (BSZ*SEQ)        // 16384
#define NSPLIT 4
#define KSPL (HID/NSPLIT)     // 512
#define KC 64                 // k-chunk staged in LDS
#define BT 64                 // tokens per block

#define XS 80                 // stride 80 ≡ 16 mod 32: kof-groups phase-aligned -> conflict-free frag reads
#define WS2 80                // wlds2 row stride [k][col*4+nt]

typedef double f64x4 __attribute__((ext_vector_type(4)));

// ---------------- Kernel 1: gate GEMM on the fp64 matrix pipe ----------------
// Block: 256 thr (4 waves), 64 tok x 64 exp, k-split 4. Wave w: tokens w*16..w*16+15.
// Per K=4 step per thread: 1 ds_read_b32 (A) + 1 ds_read_b128 (B, packed [k][col][nt])
// + 5 cvt + 4 MFMA f64. D-layout decoded at runtime via two probe MFMAs (layout-proof).
__global__ __launch_bounds__(256, 4)
void moe_gate_gemm(const float* __restrict__ x, const float* __restrict__ W,
                   float* __restrict__ part) {
    __shared__ float xlds[KC * XS];    // [k][tok], fp32
    __shared__ float wlds2[KC * WS2];  // [k][col*4+nt] = W[nt*16+col][k], fp32

    const int tid   = threadIdx.x;
    const int tile  = blockIdx.x;   // 0..255 token tile
    const int split = blockIdx.y;   // 0..3 k split
    const int T0 = tile * BT;
    const int k0 = split * KSPL;

    const int wv   = tid >> 6;      // wave 0..3
    const int lane = tid & 63;
    const int kof  = lane >> 4;     // frag k offset 0..3
    const int col  = lane & 15;     // frag row/col 0..15

    const int srow = tid & 63;      // staging row: token (x) / expert (W)

    // ---- layout calibration: decode D-fragment (row, col) per register ----
    const double a1 = (kof == 0) ? (double)col : 0.0;  // A[i][k] = i at k=0
    const double b1 = (kof == 0) ? 1.0 : 0.0;          // B[k][j] = 1 at k=0
    const double a2 = (kof == 0) ? 1.0 : 0.0;
    const double b2 = (kof == 0) ? (double)col : 0.0;  // B[k][j] = j at k=0
    const f64x4 zero = (f64x4){0.0, 0.0, 0.0, 0.0};
    const f64x4 cal1 = __builtin_amdgcn_mfma_f64_16x16x4f64(a1, b1, zero, 0, 0, 0);
    const f64x4 cal2 = __builtin_amdgcn_mfma_f64_16x16x4f64(a2, b2, zero, 0, 0, 0);
    int drow[4], dcol[4];
    #pragma unroll
    for (int a = 0; a < 4; a++) {
        drow[a] = (int)cal1[a];   // this lane's reg a holds D[drow][dcol]
        dcol[a] = (int)cal2[a];
    }

    f64x4 acc[4];
    #pragma unroll
    for (int nt = 0; nt < 4; nt++) acc[nt] = zero;

    const int base_a = kof * XS  + wv * 16 + col;  // A frag fp32 index (plus kb*4*XS)
    const int base_b = kof * WS2 + col * 4;        // B frag b128 base  (plus kb*4*WS2)

    float4 px[4], pw[4];
    // prologue: load chunk 0
    #pragma unroll
    for (int r = 0; r < 4; r++) {
        const int k4 = wv * 4 + r;
        px[r] = *reinterpret_cast<const float4*>(&x[(size_t)(T0 + srow) * HID + k0 + k4 * 4]);
        pw[r] = *reinterpret_cast<const float4*>(&W[(size_t)srow  * HID + k0 + k4 * 4]);
    }

    const int wcol = (srow & 15) * 4 + (srow >> 4);  // wlds2 in-row index for expert srow

    for (int c = 0; c < KSPL / KC; c++) {
        __syncthreads();   // previous chunk's compute reads done; LDS reusable
        #pragma unroll
        for (int r = 0; r < 4; r++) {
            const int k4 = wv * 4 + r;
            xlds[(k4 * 4 + 0) * XS + srow] = px[r].x;
            xlds[(k4 * 4 + 1) * XS + srow] = px[r].y;
            xlds[(k4 * 4 + 2) * XS + srow] = px[r].z;
            xlds[(k4 * 4 + 3) * XS + srow] = px[r].w;
            wlds2[(k4 * 4 + 0) * WS2 + wcol] = pw[r].x;
            wlds2[(k4 * 4 + 1) * WS2 + wcol] = pw[r].y;
            wlds2[(k4 * 4 + 2) * WS2 + wcol] = pw[r].z;
            wlds2[(k4 * 4 + 3) * WS2 + wcol] = pw[r].w;
        }
        // issue next chunk's global loads early (hide HBM latency under MFMA)
        if (c + 1 < KSPL / KC) {
            const int kc = k0 + (c + 1) * KC;
            #pragma unroll
            for (int r = 0; r < 4; r++) {
                const int k4 = wv * 4 + r;
                px[r] = *reinterpret_cast<const float4*>(&x[(size_t)(T0 + srow) * HID + kc + k4 * 4]);
                pw[r] = *reinterpret_cast<const float4*>(&W[(size_t)srow  * HID + kc + k4 * 4]);
            }
        }
        __syncthreads();

        #pragma unroll
        for (int kb = 0; kb < KC / 4; kb++) {
            const double ad = (double)xlds[kb * (4 * XS) + base_a];
            const float4 bf = *reinterpret_cast<const float4*>(&wlds2[kb * (4 * WS2) + base_b]);
            acc[0] = __builtin_amdgcn_mfma_f64_16x16x4f64(ad, (double)bf.x, acc[0], 0, 0, 0);
            acc[1] = __builtin_amdgcn_mfma_f64_16x16x4f64(ad, (double)bf.y, acc[1], 0, 0, 0);
            acc[2] = __builtin_amdgcn_mfma_f64_16x16x4f64(ad, (double)bf.z, acc[2], 0, 0, 0);
            acc[3] = __builtin_amdgcn_mfma_f64_16x16x4f64(ad, (double)bf.w, acc[3], 0, 0, 0);
        }
    }

    // epilogue: scatter via calibrated (row, col) — layout-proof
    #pragma unroll
    for (int nt = 0; nt < 4; nt++) {
        #pragma unroll
        for (int a = 0; a < 4; a++) {
            const int tok = T0 + wv * 16 + drow[a];
            const int e   = nt * 16 + dcol[a];
            part[((size_t)split * NTOK + tok) * NE + e] = (float)acc[nt][a];
        }
    }
}

// ---------------- Kernel 2: reduce partials + bias, top-8, masked softmax ----------------
// NOTE: ids are written as FLOAT values — the harness reads the whole d_out
// buffer as float32 (output 0's dtype) before splitting into chunks.
__global__ __launch_bounds__(256)
void moe_topk_softmax(const float* __restrict__ part, const float* __restrict__ b,
                      float* __restrict__ probs, float* __restrict__ ids) {
    const int lane  = threadIdx.x & 63;
    const int w     = threadIdx.x >> 6;
    const int token = blockIdx.x * 4 + w;

    // deterministic fixed-order reduction of the 4 k-split partials
    float g = b[lane];
    #pragma unroll
    for (int s = 0; s < NSPLIT; s++)
        g += part[((size_t)s * NTOK + token) * NE + lane];

    const float gorig = g;
    float cur = g;
    float m = 0.f, denom = 0.f;
    int   myid = 0;
    bool  sel = false;

    #pragma unroll
    for (int it = 0; it < TOPK; it++) {
        // wave argmax with lower-index tie-break (jax.lax.top_k stability)
        float v = cur;
        int idx = lane;
        #pragma unroll
        for (int d = 1; d < 64; d <<= 1) {
            const float ov = __shfl_xor(v, d, 64);
            const int   oi = __shfl_xor(idx, d, 64);
            if (ov > v || (ov == v && oi < idx)) { v = ov; idx = oi; }
        }
        if (it == 0) m = v;
        denom += expf(v - m);
        if (lane == idx) { sel = true; cur = -INFINITY; }
        if (lane == it)  myid = idx;   // lane `it` holds the it-th id (descending order)
    }

    probs[(size_t)token * NE + lane] = sel ? expf(gorig - m) / denom : 0.f;
    if (lane < TOPK) ids[(size_t)token * TOPK + lane] = (float)myid;
}

// ---------------- launch ----------------
extern "C" void kernel_launch(void* const* d_in, const int* in_sizes, int n_in,
                              void* d_out, int out_size, void* d_ws, size_t ws_size,
                              hipStream_t stream) {
    const float* x = (const float*)d_in[0];
    const float* W = (const float*)d_in[1];
    const float* b = (const float*)d_in[2];

    float* probs = (float*)d_out;                         // NTOK*NE floats
    float* ids   = (float*)d_out + (size_t)NTOK * NE;     // NTOK*TOPK, written as float
    float* part  = (float*)d_ws;                          // NSPLIT*NTOK*NE floats = 16 MiB

    dim3 g1(NTOK / BT, NSPLIT);
    moe_gate_gemm<<<g1, 256, 0, stream>>>(x, W, part);
    moe_topk_softmax<<<NTOK / 4, 256, 0, stream>>>(part, b, probs, ids);
}

// Round 8
// 245.066 us; speedup vs baseline: 1.1544x; 1.0135x over previous
//
#include <hip/hip_runtime.h>
#include <math.h>

#define BSZ 4
#define SEQ 4096
#define HID 2048
#define NE 64
#define TOPK 8
#define NTOK (BSZ*SEQ)        // 16384
#define NSPLIT 4
#define KSPL (HID/NSPLIT)     // 512
#define KC 32                 // k-chunk per stage (double-buffered)
#define NCH (KSPL/KC)         // 16 chunks
#define BT 64                 // tokens per block

#define XS 80                 // stride ≡16 mod 32: frag reads conflict-free (verified R6)
#define WS2 80
#define XBUF (KC*XS)          // floats per x buffer
#define WBUF (KC*WS2)

typedef double f64x4 __attribute__((ext_vector_type(4)));

// ---------------- Kernel 1: gate GEMM, fp64 MFMA, 2-phase double-buffered ----------------
// Per chunk: compute c from buf[cur] (8x {ds_read_b32 + ds_read_b128 + 4 MFMA f64})
// while regs holding chunk c+1 (global-loaded one full chunk earlier) are written to
// buf[nxt]; ONE barrier per chunk. D-layout decoded at runtime via probe MFMAs.
__global__ __launch_bounds__(256, 4)
void moe_gate_gemm(const float* __restrict__ x, const float* __restrict__ W,
                   float* __restrict__ part) {
    __shared__ float xlds[2 * XBUF];   // [buf][k][tok]
    __shared__ float wlds2[2 * WBUF];  // [buf][k][col*4+nt] = W[nt*16+col][k]

    const int tid   = threadIdx.x;
    const int tile  = blockIdx.x;   // 0..255 token tile
    const int split = blockIdx.y;   // 0..3 k split
    const int T0 = tile * BT;
    const int k0 = split * KSPL;

    const int wv   = tid >> 6;      // wave 0..3
    const int lane = tid & 63;
    const int kof  = lane >> 4;     // frag k offset 0..3
    const int col  = lane & 15;     // frag row/col 0..15

    const int srow = tid & 63;      // staging row: token (x) / expert (W)
    const int wcol = (srow & 15) * 4 + (srow >> 4);  // wlds2 in-row index for expert srow

    // ---- layout calibration: decode D-fragment (row, col) per register ----
    const double a1 = (kof == 0) ? (double)col : 0.0;  // A[i][k] = i at k=0
    const double b1 = (kof == 0) ? 1.0 : 0.0;          // B[k][j] = 1 at k=0
    const double a2 = (kof == 0) ? 1.0 : 0.0;
    const double b2 = (kof == 0) ? (double)col : 0.0;  // B[k][j] = j at k=0
    const f64x4 zero = (f64x4){0.0, 0.0, 0.0, 0.0};
    const f64x4 cal1 = __builtin_amdgcn_mfma_f64_16x16x4f64(a1, b1, zero, 0, 0, 0);
    const f64x4 cal2 = __builtin_amdgcn_mfma_f64_16x16x4f64(a2, b2, zero, 0, 0, 0);
    int drow[4], dcol[4];
    #pragma unroll
    for (int a = 0; a < 4; a++) {
        drow[a] = (int)cal1[a];   // this lane's reg a holds D[drow][dcol]
        dcol[a] = (int)cal2[a];
    }

    f64x4 acc[4];
    #pragma unroll
    for (int nt = 0; nt < 4; nt++) acc[nt] = zero;

    const int base_a = kof * XS  + wv * 16 + col;  // A frag fp32 index (+ kb*4*XS)
    const int base_b = kof * WS2 + col * 4;        // B frag b128 base  (+ kb*4*WS2)

    float4 px[2], pw[2];

#define STAGE_LOAD(KOFF)                                                              \
    {                                                                                 \
        _Pragma("unroll")                                                             \
        for (int r = 0; r < 2; r++) {                                                 \
            const int k4 = wv * 2 + r;                                                \
            px[r] = *reinterpret_cast<const float4*>(                                 \
                &x[(size_t)(T0 + srow) * HID + (KOFF) + k4 * 4]);                     \
            pw[r] = *reinterpret_cast<const float4*>(                                 \
                &W[(size_t)srow * HID + (KOFF) + k4 * 4]);                            \
        }                                                                             \
    }

#define STAGE_WRITE(XB, WB)                                                           \
    {                                                                                 \
        _Pragma("unroll")                                                             \
        for (int r = 0; r < 2; r++) {                                                 \
            const int k4 = wv * 2 + r;                                                \
            xlds[(XB) + (k4 * 4 + 0) * XS + srow] = px[r].x;                          \
            xlds[(XB) + (k4 * 4 + 1) * XS + srow] = px[r].y;                          \
            xlds[(XB) + (k4 * 4 + 2) * XS + srow] = px[r].z;                          \
            xlds[(XB) + (k4 * 4 + 3) * XS + srow] = px[r].w;                          \
            wlds2[(WB) + (k4 * 4 + 0) * WS2 + wcol] = pw[r].x;                        \
            wlds2[(WB) + (k4 * 4 + 1) * WS2 + wcol] = pw[r].y;                        \
            wlds2[(WB) + (k4 * 4 + 2) * WS2 + wcol] = pw[r].z;                        \
            wlds2[(WB) + (k4 * 4 + 3) * WS2 + wcol] = pw[r].w;                        \
        }                                                                             \
    }

#define COMPUTE(XB, WB)                                                               \
    {                                                                                 \
        __builtin_amdgcn_s_setprio(1);                                                \
        _Pragma("unroll")                                                             \
        for (int kb = 0; kb < KC / 4; kb++) {                                         \
            const double ad = (double)xlds[(XB) + kb * (4 * XS) + base_a];            \
            const float4 bf = *reinterpret_cast<const float4*>(                       \
                &wlds2[(WB) + kb * (4 * WS2) + base_b]);                              \
            acc[0] = __builtin_amdgcn_mfma_f64_16x16x4f64(ad, (double)bf.x, acc[0], 0, 0, 0); \
            acc[1] = __builtin_amdgcn_mfma_f64_16x16x4f64(ad, (double)bf.y, acc[1], 0, 0, 0); \
            acc[2] = __builtin_amdgcn_mfma_f64_16x16x4f64(ad, (double)bf.z, acc[2], 0, 0, 0); \
            acc[3] = __builtin_amdgcn_mfma_f64_16x16x4f64(ad, (double)bf.w, acc[3], 0, 0, 0); \
        }                                                                             \
        __builtin_amdgcn_s_setprio(0);                                                \
    }

    // prologue: chunk0 -> regs -> buf0; issue chunk1 loads
    STAGE_LOAD(k0);
    STAGE_WRITE(0, 0);
    STAGE_LOAD(k0 + KC);
    __syncthreads();

    // invariant at top of iteration t: buf0 = chunk 2t (ready), regs = chunk 2t+1 (in flight)
    for (int t = 0; t < NCH / 2; ++t) {
        const int c0 = 2 * t;
        // body A: compute chunk c0 from buf0; write chunk c0+1 to buf1
        COMPUTE(0, 0);
        STAGE_WRITE(XBUF, WBUF);
        if (c0 + 2 < NCH) STAGE_LOAD(k0 + (c0 + 2) * KC);
        __syncthreads();
        // body B: compute chunk c0+1 from buf1; write chunk c0+2 to buf0
        COMPUTE(XBUF, WBUF);
        if (c0 + 2 < NCH) {
            STAGE_WRITE(0, 0);
            if (c0 + 3 < NCH) STAGE_LOAD(k0 + (c0 + 3) * KC);
            __syncthreads();
        }
    }

    // epilogue: scatter via calibrated (row, col) — layout-proof
    #pragma unroll
    for (int nt = 0; nt < 4; nt++) {
        #pragma unroll
        for (int a = 0; a < 4; a++) {
            const int tok = T0 + wv * 16 + drow[a];
            const int e   = nt * 16 + dcol[a];
            part[((size_t)split * NTOK + tok) * NE + e] = (float)acc[nt][a];
        }
    }
#undef STAGE_LOAD
#undef STAGE_WRITE
#undef COMPUTE
}

// ---------------- Kernel 2: reduce partials + bias, top-8, masked softmax ----------------
// NOTE: ids are written as FLOAT values — the harness reads the whole d_out
// buffer as float32 (output 0's dtype) before splitting into chunks.
__global__ __launch_bounds__(256)
void moe_topk_softmax(const float* __restrict__ part, const float* __restrict__ b,
                      float* __restrict__ probs, float* __restrict__ ids) {
    const int lane  = threadIdx.x & 63;
    const int w     = threadIdx.x >> 6;
    const int token = blockIdx.x * 4 + w;

    // deterministic fixed-order reduction of the 4 k-split partials
    float g = b[lane];
    #pragma unroll
    for (int s = 0; s < NSPLIT; s++)
        g += part[((size_t)s * NTOK + token) * NE + lane];

    const float gorig = g;
    float cur = g;
    float m = 0.f, denom = 0.f;
    int   myid = 0;
    bool  sel = false;

    #pragma unroll
    for (int it = 0; it < TOPK; it++) {
        // wave argmax with lower-index tie-break (jax.lax.top_k stability)
        float v = cur;
        int idx = lane;
        #pragma unroll
        for (int d = 1; d < 64; d <<= 1) {
            const float ov = __shfl_xor(v, d, 64);
            const int   oi = __shfl_xor(idx, d, 64);
            if (ov > v || (ov == v && oi < idx)) { v = ov; idx = oi; }
        }
        if (it == 0) m = v;
        denom += expf(v - m);
        if (lane == idx) { sel = true; cur = -INFINITY; }
        if (lane == it)  myid = idx;   // lane `it` holds the it-th id (descending order)
    }

    probs[(size_t)token * NE + lane] = sel ? expf(gorig - m) / denom : 0.f;
    if (lane < TOPK) ids[(size_t)token * TOPK + lane] = (float)myid;
}

// ---------------- launch ----------------
extern "C" void kernel_launch(void* const* d_in, const int* in_sizes, int n_in,
                              void* d_out, int out_size, void* d_ws, size_t ws_size,
                              hipStream_t stream) {
    const float* x = (const float*)d_in[0];
    const float* W = (const float*)d_in[1];
    const float* b = (const float*)d_in[2];

    float* probs = (float*)d_out;                         // NTOK*NE floats
    float* ids   = (float*)d_out + (size_t)NTOK * NE;     // NTOK*TOPK, written as float
    float* part  = (float*)d_ws;                          // NSPLIT*NTOK*NE floats = 16 MiB

    dim3 g1(NTOK / BT, NSPLIT);
    moe_gate_gemm<<<g1, 256, 0, stream>>>(x, W, part);
    moe_topk_softmax<<<NTOK / 4, 256, 0, stream>>>(part, b, probs, ids);
}